// Round 15
// baseline (100.270 us; speedup 1.0000x reference)
//
#include <hip/hip_runtime.h>

#define L    2048
#define HALF 1024
#define NM   10
#define NG   20
#define NF   30

#define NCC2 2000   // coarse blocks = (m, i2, i3-pair)
#define NFC2 450    // fine blocks   = (j2, j3-pair)

// ---- float workspace layout (float indices) ----
#define OFF_SC   0                        // float2 sc[1024] = {sin^2, sin*td}
#define OFF_TAB  2048                     // float2 tab[NM*HALF] = {lc, ls}
#define OFF_G20  (2048 + 2*NM*HALF)       // 22528: grid20[20]
#define OFF_R20  (OFF_G20 + 20)           // -1/grid20 [20]
#define OFF_DWS  (OFF_R20 + 20)           // 22568 floats -> byte 90272 (%8==0)

#define EXP2F(x) __builtin_amdgcn_exp2f(x)
#define LOG2F(x) __builtin_amdgcn_logf(x)

__device__ __forceinline__ float grid20(int i) {
  double e = -1.0 + 2.0 * (double)i / 19.0;
  return (float)exp2(e * 3.3219280948873623478703194294894);
}
__device__ __forceinline__ float finev(float c, int j) {
  return (float)((double)c * 0.8 + (double)j * ((double)c * 0.4 / 29.0));
}
__device__ __forceinline__ double mse_from(double sgg2, double sgt, double sum_tt) {
  double S = sgg2; if (S < 0.0) S = 0.0;
  double d = sqrt(S / (double)(L - 1)) + 1e-6;
  return (S / (d * d) - 2.0 * sgt / d + sum_tt) / (double)L;
}
__device__ __forceinline__ void vt_wave_reduce(double& v, int& t) {
  for (int o = 32; o > 0; o >>= 1) {
    double ov = __shfl_down(v, o);
    int ot = __shfl_down(t, o);
    if (ov < v || (ov == v && ot < t)) { v = ov; t = ot; }
  }
}
__device__ __forceinline__ void vt_block_merge(double& v, int& t, double* sv, int* st) {
  int lane = threadIdx.x & 63, w = threadIdx.x >> 6;
  vt_wave_reduce(v, t);
  if (lane == 0) { sv[w] = v; st[w] = t; }
  __syncthreads();
  if (threadIdx.x == 0) {
    for (int k = 1; k < 4; k++)
      if (sv[k] < v || (sv[k] == v && st[k] < t)) { v = sv[k]; t = st[k]; }
  }
}

// ---------------- K1: setup (block 0) + tables (blocks 1..4, recurrence) ---
__global__ __launch_bounds__(256) void k_init(const float* __restrict__ x,
                                              const int* __restrict__ freqp,
                                              float* __restrict__ fws,
                                              double* __restrict__ dstt) {
  if (blockIdx.x == 0) {
    int tid = threadIdx.x;
    int lane = tid & 63, w = tid >> 6;
    __shared__ double sh[8];
    __shared__ double s_mean, s_d;

    double sx = 0.0, sxx = 0.0;
    for (int l = tid; l < L; l += 256) {
      double v = (double)x[l];
      sx += v; sxx += v * v;
    }
    for (int o = 32; o > 0; o >>= 1) { sx += __shfl_down(sx, o); sxx += __shfl_down(sxx, o); }
    if (lane == 0) { sh[w] = sx; sh[4 + w] = sxx; }
    __syncthreads();
    if (tid == 0) {
      sx = sh[0] + sh[1] + sh[2] + sh[3];
      sxx = sh[4] + sh[5] + sh[6] + sh[7];
      double mean = sx / (double)L;
      double S = sxx - sx * sx / (double)L; if (S < 0.0) S = 0.0;
      s_mean = mean; s_d = sqrt(S / (double)(L - 1)) + 1e-6;
    }
    __syncthreads();
    double mean = s_mean, d = s_d;
    double freq = (double)freqp[0];

    double stt = 0.0;
    for (int l = tid; l < HALF; l += 256) {
      float tva = (float)(((double)x[l] - mean) / d);
      float tvb = (float)(((double)x[L - 1 - l] - mean) / d);
      float tdv = tva - tvb;
      double t = -1.0 + 2.0 * (double)l / 2047.0;
      float spv = (float)sin(6.2831853071795864769 * freq * t);
      float2 scv; scv.x = spv * spv; scv.y = spv * tdv;
      reinterpret_cast<float2*>(fws + OFF_SC)[l] = scv;
      stt += (double)tva * (double)tva + (double)tvb * (double)tvb;
    }
    for (int o = 32; o > 0; o >>= 1) { stt += __shfl_down(stt, o); }
    __syncthreads();
    if (lane == 0) { sh[w] = stt; }
    __syncthreads();
    if (tid == 0) { dstt[0] = sh[0] + sh[1] + sh[2] + sh[3]; }
  } else {
    // blocks 1..4: one thread per l; sincos once, then 10 angle-addition steps
    int l = (blockIdx.x - 1) * 256 + threadIdx.x;   // [0, 1024)
    double freq = (double)freqp[0];
    double t = -1.0 + 2.0 * (double)l / 2047.0;
    double theta = 6.2831853071795864769 * freq * t * 0.25;   // phi/4
    double s1, c1;
    sincos(theta, &s1, &c1);
    double sk = s1, ck = c1;
    float2* tabp = reinterpret_cast<float2*>(fws + OFF_TAB);
#pragma unroll
    for (int m = 0; m < NM; ++m) {
      float2 v;
      v.x = fmaxf(LOG2F(fabsf((float)ck)), -1.0e4f);
      v.y = fmaxf(LOG2F(fabsf((float)sk)), -1.0e4f);
      tabp[m * HALF + l] = v;
      double sn = sk * c1 + ck * s1;
      double cn = ck * c1 - sk * s1;
      sk = sn; ck = cn;
    }
    if (blockIdx.x == 1 && threadIdx.x < NG) {
      float g = grid20(threadIdx.x);
      fws[OFF_G20 + threadIdx.x] = g;
      fws[OFF_R20 + threadIdx.x] = -1.0f / g;
    }
  }
}

// ---------------- K2: coarse scan — fused THREAD-PARALLEL f64 finalize -----
__global__ __launch_bounds__(256) void k_coarse(const float* __restrict__ fws,
                                                const double* __restrict__ dstt,
                                                double* __restrict__ bv,
                                                int* __restrict__ bt) {
  __shared__ float4 row[HALF];   // 16 KB
  __shared__ float2 cells[40];
  __shared__ int cellt[40];
  int tid = threadIdx.x, lane = tid & 63, w = tid >> 6;
  int b = blockIdx.x;
  int m = b / 200;
  int rem = b % 200;
  int i2 = rem / 10;
  int p3 = rem % 10;
  int i3A = 2 * p3;
  float n2 = fws[OFF_G20 + i2];
  float n3A = fws[OFF_G20 + i3A];
  float n3B = fws[OFF_G20 + i3A + 1];

  const float2* tab = reinterpret_cast<const float2*>(fws + OFF_TAB) + m * HALF;
  const float2* sc = reinterpret_cast<const float2*>(fws + OFF_SC);
#pragma unroll
  for (int k = 0; k < 4; k++) {
    int l = tid + k * 256;
    float2 tb = tab[l];
    float2 s = sc[l];
    float a2 = EXP2F(n2 * tb.x);
    float4 v;
    v.x = LOG2F(a2 + EXP2F(n3A * tb.y));
    v.w = LOG2F(a2 + EXP2F(n3B * tb.y));
    v.y = s.x; v.z = s.y;
    row[l] = v;
  }
  __syncthreads();

#pragma unroll
  for (int pass = 0; pass < 3; ++pass) {
    const bool two = (pass < 2);
    int i1a = w * 5 + pass * 2;
    float r0 = fws[OFF_R20 + i1a];
    float r1 = two ? fws[OFF_R20 + i1a + 1] : 0.0f;
    float aA0 = 0.0f, tA0 = 0.0f, aB0 = 0.0f, tB0 = 0.0f;
    float aA1 = 0.0f, tA1 = 0.0f, aB1 = 0.0f, tB1 = 0.0f;
#pragma unroll 4
    for (int it = 0; it < 16; ++it) {
      float4 v = row[lane + it * 64];
      float eA0 = EXP2F(r0 * v.x);
      aA0 = fmaf(eA0 * eA0, v.y, aA0);
      tA0 = fmaf(eA0, v.z, tA0);
      float eB0 = EXP2F(r0 * v.w);
      aB0 = fmaf(eB0 * eB0, v.y, aB0);
      tB0 = fmaf(eB0, v.z, tB0);
      if (two) {
        float eA1 = EXP2F(r1 * v.x);
        aA1 = fmaf(eA1 * eA1, v.y, aA1);
        tA1 = fmaf(eA1, v.z, tA1);
        float eB1 = EXP2F(r1 * v.w);
        aB1 = fmaf(eB1 * eB1, v.y, aB1);
        tB1 = fmaf(eB1, v.z, tB1);
      }
    }
    for (int o = 32; o > 0; o >>= 1) {
      aA0 += __shfl_down(aA0, o); tA0 += __shfl_down(tA0, o);
      aB0 += __shfl_down(aB0, o); tB0 += __shfl_down(tB0, o);
      if (two) {
        aA1 += __shfl_down(aA1, o); tA1 += __shfl_down(tA1, o);
        aB1 += __shfl_down(aB1, o); tB1 += __shfl_down(tB1, o);
      }
    }
    if (lane == 0) {
      int t0 = ((m * NG + i1a) * NG + i2) * NG + i3A;   // ref flat index
      int s0 = w * 10 + pass * 4;
      cells[s0]     = make_float2(aA0, tA0); cellt[s0]     = t0;
      cells[s0 + 1] = make_float2(aB0, tB0); cellt[s0 + 1] = t0 + 1;
      if (two) {
        cells[s0 + 2] = make_float2(aA1, tA1); cellt[s0 + 2] = t0 + NG * NG;
        cells[s0 + 3] = make_float2(aB1, tB1); cellt[s0 + 3] = t0 + NG * NG + 1;
      }
    }
  }
  __syncthreads();

  if (w == 0) {
    double v = 1e300; int t = 0x7fffffff;
    if (lane < 40) {
      float2 p = cells[lane];
      v = mse_from(2.0 * (double)p.x, (double)p.y, dstt[0]);
      t = cellt[lane];
    }
    vt_wave_reduce(v, t);
    if (lane == 0) { bv[b] = v; bt[b] = t; }
  }
}

// ---------------- K3: fine scan — coarse argmin preamble, fused finalize ---
__global__ __launch_bounds__(256) void k_fine(const float* __restrict__ fws,
                                              const double* __restrict__ dstt,
                                              const double* __restrict__ bvc,
                                              const int* __restrict__ btc,
                                              double* __restrict__ bvf,
                                              int* __restrict__ btf) {
  __shared__ float4 row[HALF];
  __shared__ float2 cells[60];
  __shared__ int cellt[60];
  __shared__ double sv[4];
  __shared__ int st[4];
  __shared__ float s_cn[4];
  {
    double v = 1e300; int t = 0x7fffffff;
    for (int i = threadIdx.x; i < NCC2; i += 256) {
      double ov = bvc[i]; int ot = btc[i];
      if (ov < v || (ov == v && ot < t)) { v = ov; t = ot; }
    }
    vt_block_merge(v, t, sv, st);
    if (threadIdx.x == 0) {
      int ci = t;
      int m  = ci / (NG * NG * NG);
      int rr = ci % (NG * NG * NG);
      s_cn[0] = grid20(rr / (NG * NG));
      s_cn[1] = grid20((rr / NG) % NG);
      s_cn[2] = grid20(rr % NG);
      s_cn[3] = (float)m;
    }
  }
  __syncthreads();
  float cn1 = s_cn[0], cn2 = s_cn[1], cn3 = s_cn[2];
  int m = (int)s_cn[3];

  int tid = threadIdx.x, lane = tid & 63, w = tid >> 6;
  int b = blockIdx.x;
  int j2 = b / 15;
  int p3 = b % 15;
  int j3A = 2 * p3;
  float n2 = finev(cn2, j2);
  float n3A = finev(cn3, j3A);
  float n3B = finev(cn3, j3A + 1);

  const float2* tab = reinterpret_cast<const float2*>(fws + OFF_TAB) + m * HALF;
  const float2* sc = reinterpret_cast<const float2*>(fws + OFF_SC);
#pragma unroll
  for (int k = 0; k < 4; k++) {
    int l = tid + k * 256;
    float2 tb = tab[l];
    float2 s = sc[l];
    float a2 = EXP2F(n2 * tb.x);
    float4 v;
    v.x = LOG2F(a2 + EXP2F(n3A * tb.y));
    v.w = LOG2F(a2 + EXP2F(n3B * tb.y));
    v.y = s.x; v.z = s.y;
    row[l] = v;
  }
  __syncthreads();

  int npairs = (w < 3) ? 4 : 3;   // j1 counts 8,8,8,6
  for (int pp = 0; pp < npairs; ++pp) {
    int j1a = w * 8 + pp * 2;
    float r0 = -1.0f / finev(cn1, j1a);
    float r1 = -1.0f / finev(cn1, j1a + 1);
    float aA0 = 0.0f, tA0 = 0.0f, aB0 = 0.0f, tB0 = 0.0f;
    float aA1 = 0.0f, tA1 = 0.0f, aB1 = 0.0f, tB1 = 0.0f;
#pragma unroll 4
    for (int it = 0; it < 16; ++it) {
      float4 v = row[lane + it * 64];
      float eA0 = EXP2F(r0 * v.x);
      aA0 = fmaf(eA0 * eA0, v.y, aA0);
      tA0 = fmaf(eA0, v.z, tA0);
      float eB0 = EXP2F(r0 * v.w);
      aB0 = fmaf(eB0 * eB0, v.y, aB0);
      tB0 = fmaf(eB0, v.z, tB0);
      float eA1 = EXP2F(r1 * v.x);
      aA1 = fmaf(eA1 * eA1, v.y, aA1);
      tA1 = fmaf(eA1, v.z, tA1);
      float eB1 = EXP2F(r1 * v.w);
      aB1 = fmaf(eB1 * eB1, v.y, aB1);
      tB1 = fmaf(eB1, v.z, tB1);
    }
    for (int o = 32; o > 0; o >>= 1) {
      aA0 += __shfl_down(aA0, o); tA0 += __shfl_down(tA0, o);
      aB0 += __shfl_down(aB0, o); tB0 += __shfl_down(tB0, o);
      aA1 += __shfl_down(aA1, o); tA1 += __shfl_down(tA1, o);
      aB1 += __shfl_down(aB1, o); tB1 += __shfl_down(tB1, o);
    }
    if (lane == 0) {
      int t0 = (j1a * NF + j2) * NF + j3A;   // fine flat index
      int s0 = w * 16 + pp * 4;
      cells[s0]     = make_float2(aA0, tA0); cellt[s0]     = t0;
      cells[s0 + 1] = make_float2(aB0, tB0); cellt[s0 + 1] = t0 + 1;
      cells[s0 + 2] = make_float2(aA1, tA1); cellt[s0 + 2] = t0 + NF * NF;
      cells[s0 + 3] = make_float2(aB1, tB1); cellt[s0 + 3] = t0 + NF * NF + 1;
    }
  }
  __syncthreads();

  if (w == 0) {
    double v = 1e300; int t = 0x7fffffff;
    if (lane < 60) {
      float2 p = cells[lane];
      v = mse_from(2.0 * (double)p.x, (double)p.y, dstt[0]);
      t = cellt[lane];
    }
    vt_wave_reduce(v, t);
    if (lane == 0) { bvf[b] = v; btf[b] = t; }
  }
}

// ---------------- K4: final argmins + emit ---------------------------------
__global__ __launch_bounds__(256) void k_out(const double* __restrict__ bvc,
                                             const int* __restrict__ btc,
                                             const double* __restrict__ bvf,
                                             const int* __restrict__ btf,
                                             float* __restrict__ out) {
  __shared__ double sv[4];
  __shared__ int st[4];
  __shared__ int s_ci;
  {
    double v = 1e300; int t = 0x7fffffff;
    for (int i = threadIdx.x; i < NCC2; i += 256) {
      double ov = bvc[i]; int ot = btc[i];
      if (ov < v || (ov == v && ot < t)) { v = ov; t = ot; }
    }
    vt_block_merge(v, t, sv, st);
    if (threadIdx.x == 0) s_ci = t;
  }
  __syncthreads();
  {
    double v = 1e300; int t = 0x7fffffff;
    for (int i = threadIdx.x; i < NFC2; i += 256) {
      double ov = bvf[i]; int ot = btf[i];
      if (ov < v || (ov == v && ot < t)) { v = ov; t = ot; }
    }
    vt_block_merge(v, t, sv, st);
    if (threadIdx.x == 0) {
      int ci = s_ci;
      int m  = ci / (NG * NG * NG);
      int rr = ci % (NG * NG * NG);
      float cn1 = grid20(rr / (NG * NG));
      float cn2 = grid20((rr / NG) % NG);
      float cn3 = grid20(rr % NG);
      int fi = t;
      int f1 = fi / (NF * NF);
      int fc = fi % (NF * NF);
      out[0] = (float)(m + 1);
      out[1] = finev(cn1, f1);
      out[2] = finev(cn2, fc / NF);
      out[3] = finev(cn3, fc % NF);
    }
  }
}

extern "C" void kernel_launch(void* const* d_in, const int* in_sizes, int n_in,
                              void* d_out, int out_size, void* d_ws, size_t ws_size,
                              hipStream_t stream) {
  const float* x = (const float*)d_in[0];
  const int* freqp = (const int*)d_in[1];
  float* out = (float*)d_out;
  float* fws = (float*)d_ws;

  double* D0  = (double*)(fws + OFF_DWS);   // byte 90272, 8-aligned
  double* dstt = D0;                        // [1]
  double* bvc = D0 + 1;                     // NCC2
  double* bvf = bvc + NCC2;                 // NFC2
  int* btc = (int*)(bvf + NFC2);            // NCC2
  int* btf = btc + NCC2;                    // NFC2

  // MEASUREMENT ROUND: run the identical, idempotent pipeline TWICE.
  // total = fixed_overhead + 2*work  ->  decompose against r14's fixed+work.
  for (int rep = 0; rep < 2; ++rep) {
    hipLaunchKernelGGL(k_init,   dim3(5),    dim3(256), 0, stream, x, freqp, fws, dstt);
    hipLaunchKernelGGL(k_coarse, dim3(NCC2), dim3(256), 0, stream, fws, dstt, bvc, btc);
    hipLaunchKernelGGL(k_fine,   dim3(NFC2), dim3(256), 0, stream, fws, dstt, bvc, btc, bvf, btf);
    hipLaunchKernelGGL(k_out,    dim3(1),    dim3(256), 0, stream, bvc, btc, bvf, btf, out);
  }
}

// Round 16
// 69.981 us; speedup vs baseline: 1.4328x; 1.4328x over previous
//
#include <hip/hip_runtime.h>

#define L    2048
#define HALF 1024
#define NM   10
#define NG   20
#define NF   30

#define NCC2 2000   // coarse blocks = (m, i2, i3-pair)
#define NFC2 450    // fine blocks   = (j2, j3-pair)

// ---- float workspace layout (float indices) ----
#define OFF_SC   0                        // float2 sc[1024] = {sin^2, sin*td}
#define OFF_TAB  2048                     // float2 tab[NM*HALF] = {lc, ls}
#define OFF_G20  (2048 + 2*NM*HALF)       // 22528: grid20[20]
#define OFF_R20  (OFF_G20 + 20)           // -1/grid20 [20]
#define OFF_DWS  (OFF_R20 + 20)           // 22568 floats -> byte 90272 (%8==0)

#define EXP2F(x) __builtin_amdgcn_exp2f(x)
#define LOG2F(x) __builtin_amdgcn_logf(x)

// VALU-only exp2: rint + 6-FMA Cephes minimax (rel err ~2e-8) + ldexp.
// ~10 plain VALU ops (~20 cyc/wave64) vs v_exp_f32's measured ~60 cyc.
// Valid for x in [-10, 60] here (lsum in [-5,1] clamped, r in [-10,-0.1]).
__device__ __forceinline__ float fexp2(float x) {
  float n = __builtin_rintf(x);
  float f = x - n;
  float p = 1.535336188319500e-4f;
  p = fmaf(p, f, 1.339887440266574e-3f);
  p = fmaf(p, f, 9.618437357674640e-3f);
  p = fmaf(p, f, 5.550332471162809e-2f);
  p = fmaf(p, f, 2.402264791363012e-1f);
  p = fmaf(p, f, 6.931472028550421e-1f);
  p = fmaf(p, f, 1.0f);
  return __builtin_ldexpf(p, (int)n);
}

__device__ __forceinline__ float grid20(int i) {
  double e = -1.0 + 2.0 * (double)i / 19.0;
  return (float)exp2(e * 3.3219280948873623478703194294894);
}
__device__ __forceinline__ float finev(float c, int j) {
  return (float)((double)c * 0.8 + (double)j * ((double)c * 0.4 / 29.0));
}
__device__ __forceinline__ double mse_from(double sgg2, double sgt, double sum_tt) {
  double S = sgg2; if (S < 0.0) S = 0.0;
  double d = sqrt(S / (double)(L - 1)) + 1e-6;
  return (S / (d * d) - 2.0 * sgt / d + sum_tt) / (double)L;
}
__device__ __forceinline__ void vt_wave_reduce(double& v, int& t) {
  for (int o = 32; o > 0; o >>= 1) {
    double ov = __shfl_down(v, o);
    int ot = __shfl_down(t, o);
    if (ov < v || (ov == v && ot < t)) { v = ov; t = ot; }
  }
}
__device__ __forceinline__ void vt_block_merge(double& v, int& t, double* sv, int* st) {
  int lane = threadIdx.x & 63, w = threadIdx.x >> 6;
  vt_wave_reduce(v, t);
  if (lane == 0) { sv[w] = v; st[w] = t; }
  __syncthreads();
  if (threadIdx.x == 0) {
    for (int k = 1; k < 4; k++)
      if (sv[k] < v || (sv[k] == v && st[k] < t)) { v = sv[k]; t = st[k]; }
  }
}

// ---------------- K1: setup (block 0) + tables (blocks 1..4, recurrence) ---
__global__ __launch_bounds__(256) void k_init(const float* __restrict__ x,
                                              const int* __restrict__ freqp,
                                              float* __restrict__ fws,
                                              double* __restrict__ dstt) {
  if (blockIdx.x == 0) {
    int tid = threadIdx.x;
    int lane = tid & 63, w = tid >> 6;
    __shared__ double sh[8];
    __shared__ double s_mean, s_d;

    double sx = 0.0, sxx = 0.0;
    for (int l = tid; l < L; l += 256) {
      double v = (double)x[l];
      sx += v; sxx += v * v;
    }
    for (int o = 32; o > 0; o >>= 1) { sx += __shfl_down(sx, o); sxx += __shfl_down(sxx, o); }
    if (lane == 0) { sh[w] = sx; sh[4 + w] = sxx; }
    __syncthreads();
    if (tid == 0) {
      sx = sh[0] + sh[1] + sh[2] + sh[3];
      sxx = sh[4] + sh[5] + sh[6] + sh[7];
      double mean = sx / (double)L;
      double S = sxx - sx * sx / (double)L; if (S < 0.0) S = 0.0;
      s_mean = mean; s_d = sqrt(S / (double)(L - 1)) + 1e-6;
    }
    __syncthreads();
    double mean = s_mean, d = s_d;
    double freq = (double)freqp[0];

    double stt = 0.0;
    for (int l = tid; l < HALF; l += 256) {
      float tva = (float)(((double)x[l] - mean) / d);
      float tvb = (float)(((double)x[L - 1 - l] - mean) / d);
      float tdv = tva - tvb;
      double t = -1.0 + 2.0 * (double)l / 2047.0;
      float spv = (float)sin(6.2831853071795864769 * freq * t);
      float2 scv; scv.x = spv * spv; scv.y = spv * tdv;
      reinterpret_cast<float2*>(fws + OFF_SC)[l] = scv;
      stt += (double)tva * (double)tva + (double)tvb * (double)tvb;
    }
    for (int o = 32; o > 0; o >>= 1) { stt += __shfl_down(stt, o); }
    __syncthreads();
    if (lane == 0) { sh[w] = stt; }
    __syncthreads();
    if (tid == 0) { dstt[0] = sh[0] + sh[1] + sh[2] + sh[3]; }
  } else {
    // blocks 1..4: one thread per l; sincos once, then 10 angle-addition steps
    int l = (blockIdx.x - 1) * 256 + threadIdx.x;   // [0, 1024)
    double freq = (double)freqp[0];
    double t = -1.0 + 2.0 * (double)l / 2047.0;
    double theta = 6.2831853071795864769 * freq * t * 0.25;   // phi/4
    double s1, c1;
    sincos(theta, &s1, &c1);
    double sk = s1, ck = c1;
    float2* tabp = reinterpret_cast<float2*>(fws + OFF_TAB);
#pragma unroll
    for (int m = 0; m < NM; ++m) {
      float2 v;
      v.x = fmaxf(LOG2F(fabsf((float)ck)), -1.0e4f);
      v.y = fmaxf(LOG2F(fabsf((float)sk)), -1.0e4f);
      tabp[m * HALF + l] = v;
      double sn = sk * c1 + ck * s1;
      double cn = ck * c1 - sk * s1;
      sk = sn; ck = cn;
    }
    if (blockIdx.x == 1 && threadIdx.x < NG) {
      float g = grid20(threadIdx.x);
      fws[OFF_G20 + threadIdx.x] = g;
      fws[OFF_R20 + threadIdx.x] = -1.0f / g;
    }
  }
}

// ---------------- K2: coarse scan — poly exp2 in hot loop ------------------
__global__ __launch_bounds__(256) void k_coarse(const float* __restrict__ fws,
                                                const double* __restrict__ dstt,
                                                double* __restrict__ bv,
                                                int* __restrict__ bt) {
  __shared__ float4 row[HALF];   // 16 KB
  __shared__ float2 cells[40];
  __shared__ int cellt[40];
  int tid = threadIdx.x, lane = tid & 63, w = tid >> 6;
  int b = blockIdx.x;
  int m = b / 200;
  int rem = b % 200;
  int i2 = rem / 10;
  int p3 = rem % 10;
  int i3A = 2 * p3;
  float n2 = fws[OFF_G20 + i2];
  float n3A = fws[OFF_G20 + i3A];
  float n3B = fws[OFF_G20 + i3A + 1];

  const float2* tab = reinterpret_cast<const float2*>(fws + OFF_TAB) + m * HALF;
  const float2* sc = reinterpret_cast<const float2*>(fws + OFF_SC);
#pragma unroll
  for (int k = 0; k < 4; k++) {
    int l = tid + k * 256;
    float2 tb = tab[l];
    float2 s = sc[l];
    float a2 = EXP2F(n2 * tb.x);
    float4 v;
    v.x = LOG2F(a2 + EXP2F(n3A * tb.y));
    v.w = LOG2F(a2 + EXP2F(n3B * tb.y));
    v.y = s.x; v.z = s.y;
    row[l] = v;
  }
  __syncthreads();

#pragma unroll
  for (int pass = 0; pass < 3; ++pass) {
    const bool two = (pass < 2);
    int i1a = w * 5 + pass * 2;
    float r0 = fws[OFF_R20 + i1a];
    float r1 = two ? fws[OFF_R20 + i1a + 1] : 0.0f;
    float aA0 = 0.0f, tA0 = 0.0f, aB0 = 0.0f, tB0 = 0.0f;
    float aA1 = 0.0f, tA1 = 0.0f, aB1 = 0.0f, tB1 = 0.0f;
#pragma unroll 4
    for (int it = 0; it < 16; ++it) {
      float4 v = row[lane + it * 64];
      float eA0 = fexp2(r0 * v.x);
      aA0 = fmaf(eA0 * eA0, v.y, aA0);
      tA0 = fmaf(eA0, v.z, tA0);
      float eB0 = fexp2(r0 * v.w);
      aB0 = fmaf(eB0 * eB0, v.y, aB0);
      tB0 = fmaf(eB0, v.z, tB0);
      if (two) {
        float eA1 = fexp2(r1 * v.x);
        aA1 = fmaf(eA1 * eA1, v.y, aA1);
        tA1 = fmaf(eA1, v.z, tA1);
        float eB1 = fexp2(r1 * v.w);
        aB1 = fmaf(eB1 * eB1, v.y, aB1);
        tB1 = fmaf(eB1, v.z, tB1);
      }
    }
    for (int o = 32; o > 0; o >>= 1) {
      aA0 += __shfl_down(aA0, o); tA0 += __shfl_down(tA0, o);
      aB0 += __shfl_down(aB0, o); tB0 += __shfl_down(tB0, o);
      if (two) {
        aA1 += __shfl_down(aA1, o); tA1 += __shfl_down(tA1, o);
        aB1 += __shfl_down(aB1, o); tB1 += __shfl_down(tB1, o);
      }
    }
    if (lane == 0) {
      int t0 = ((m * NG + i1a) * NG + i2) * NG + i3A;   // ref flat index
      int s0 = w * 10 + pass * 4;
      cells[s0]     = make_float2(aA0, tA0); cellt[s0]     = t0;
      cells[s0 + 1] = make_float2(aB0, tB0); cellt[s0 + 1] = t0 + 1;
      if (two) {
        cells[s0 + 2] = make_float2(aA1, tA1); cellt[s0 + 2] = t0 + NG * NG;
        cells[s0 + 3] = make_float2(aB1, tB1); cellt[s0 + 3] = t0 + NG * NG + 1;
      }
    }
  }
  __syncthreads();

  if (w == 0) {
    double v = 1e300; int t = 0x7fffffff;
    if (lane < 40) {
      float2 p = cells[lane];
      v = mse_from(2.0 * (double)p.x, (double)p.y, dstt[0]);
      t = cellt[lane];
    }
    vt_wave_reduce(v, t);
    if (lane == 0) { bv[b] = v; bt[b] = t; }
  }
}

// ---------------- K3: fine scan — coarse argmin preamble, poly exp2 --------
__global__ __launch_bounds__(256) void k_fine(const float* __restrict__ fws,
                                              const double* __restrict__ dstt,
                                              const double* __restrict__ bvc,
                                              const int* __restrict__ btc,
                                              double* __restrict__ bvf,
                                              int* __restrict__ btf) {
  __shared__ float4 row[HALF];
  __shared__ float2 cells[60];
  __shared__ int cellt[60];
  __shared__ double sv[4];
  __shared__ int st[4];
  __shared__ float s_cn[4];
  {
    double v = 1e300; int t = 0x7fffffff;
    for (int i = threadIdx.x; i < NCC2; i += 256) {
      double ov = bvc[i]; int ot = btc[i];
      if (ov < v || (ov == v && ot < t)) { v = ov; t = ot; }
    }
    vt_block_merge(v, t, sv, st);
    if (threadIdx.x == 0) {
      int ci = t;
      int m  = ci / (NG * NG * NG);
      int rr = ci % (NG * NG * NG);
      s_cn[0] = grid20(rr / (NG * NG));
      s_cn[1] = grid20((rr / NG) % NG);
      s_cn[2] = grid20(rr % NG);
      s_cn[3] = (float)m;
    }
  }
  __syncthreads();
  float cn1 = s_cn[0], cn2 = s_cn[1], cn3 = s_cn[2];
  int m = (int)s_cn[3];

  int tid = threadIdx.x, lane = tid & 63, w = tid >> 6;
  int b = blockIdx.x;
  int j2 = b / 15;
  int p3 = b % 15;
  int j3A = 2 * p3;
  float n2 = finev(cn2, j2);
  float n3A = finev(cn3, j3A);
  float n3B = finev(cn3, j3A + 1);

  const float2* tab = reinterpret_cast<const float2*>(fws + OFF_TAB) + m * HALF;
  const float2* sc = reinterpret_cast<const float2*>(fws + OFF_SC);
#pragma unroll
  for (int k = 0; k < 4; k++) {
    int l = tid + k * 256;
    float2 tb = tab[l];
    float2 s = sc[l];
    float a2 = EXP2F(n2 * tb.x);
    float4 v;
    v.x = LOG2F(a2 + EXP2F(n3A * tb.y));
    v.w = LOG2F(a2 + EXP2F(n3B * tb.y));
    v.y = s.x; v.z = s.y;
    row[l] = v;
  }
  __syncthreads();

  int npairs = (w < 3) ? 4 : 3;   // j1 counts 8,8,8,6
  for (int pp = 0; pp < npairs; ++pp) {
    int j1a = w * 8 + pp * 2;
    float r0 = -1.0f / finev(cn1, j1a);
    float r1 = -1.0f / finev(cn1, j1a + 1);
    float aA0 = 0.0f, tA0 = 0.0f, aB0 = 0.0f, tB0 = 0.0f;
    float aA1 = 0.0f, tA1 = 0.0f, aB1 = 0.0f, tB1 = 0.0f;
#pragma unroll 4
    for (int it = 0; it < 16; ++it) {
      float4 v = row[lane + it * 64];
      float eA0 = fexp2(r0 * v.x);
      aA0 = fmaf(eA0 * eA0, v.y, aA0);
      tA0 = fmaf(eA0, v.z, tA0);
      float eB0 = fexp2(r0 * v.w);
      aB0 = fmaf(eB0 * eB0, v.y, aB0);
      tB0 = fmaf(eB0, v.z, tB0);
      float eA1 = fexp2(r1 * v.x);
      aA1 = fmaf(eA1 * eA1, v.y, aA1);
      tA1 = fmaf(eA1, v.z, tA1);
      float eB1 = fexp2(r1 * v.w);
      aB1 = fmaf(eB1 * eB1, v.y, aB1);
      tB1 = fmaf(eB1, v.z, tB1);
    }
    for (int o = 32; o > 0; o >>= 1) {
      aA0 += __shfl_down(aA0, o); tA0 += __shfl_down(tA0, o);
      aB0 += __shfl_down(aB0, o); tB0 += __shfl_down(tB0, o);
      aA1 += __shfl_down(aA1, o); tA1 += __shfl_down(tA1, o);
      aB1 += __shfl_down(aB1, o); tB1 += __shfl_down(tB1, o);
    }
    if (lane == 0) {
      int t0 = (j1a * NF + j2) * NF + j3A;   // fine flat index
      int s0 = w * 16 + pp * 4;
      cells[s0]     = make_float2(aA0, tA0); cellt[s0]     = t0;
      cells[s0 + 1] = make_float2(aB0, tB0); cellt[s0 + 1] = t0 + 1;
      cells[s0 + 2] = make_float2(aA1, tA1); cellt[s0 + 2] = t0 + NF * NF;
      cells[s0 + 3] = make_float2(aB1, tB1); cellt[s0 + 3] = t0 + NF * NF + 1;
    }
  }
  __syncthreads();

  if (w == 0) {
    double v = 1e300; int t = 0x7fffffff;
    if (lane < 60) {
      float2 p = cells[lane];
      v = mse_from(2.0 * (double)p.x, (double)p.y, dstt[0]);
      t = cellt[lane];
    }
    vt_wave_reduce(v, t);
    if (lane == 0) { bvf[b] = v; btf[b] = t; }
  }
}

// ---------------- K4: final argmins + emit ---------------------------------
__global__ __launch_bounds__(256) void k_out(const double* __restrict__ bvc,
                                             const int* __restrict__ btc,
                                             const double* __restrict__ bvf,
                                             const int* __restrict__ btf,
                                             float* __restrict__ out) {
  __shared__ double sv[4];
  __shared__ int st[4];
  __shared__ int s_ci;
  {
    double v = 1e300; int t = 0x7fffffff;
    for (int i = threadIdx.x; i < NCC2; i += 256) {
      double ov = bvc[i]; int ot = btc[i];
      if (ov < v || (ov == v && ot < t)) { v = ov; t = ot; }
    }
    vt_block_merge(v, t, sv, st);
    if (threadIdx.x == 0) s_ci = t;
  }
  __syncthreads();
  {
    double v = 1e300; int t = 0x7fffffff;
    for (int i = threadIdx.x; i < NFC2; i += 256) {
      double ov = bvf[i]; int ot = btf[i];
      if (ov < v || (ov == v && ot < t)) { v = ov; t = ot; }
    }
    vt_block_merge(v, t, sv, st);
    if (threadIdx.x == 0) {
      int ci = s_ci;
      int m  = ci / (NG * NG * NG);
      int rr = ci % (NG * NG * NG);
      float cn1 = grid20(rr / (NG * NG));
      float cn2 = grid20((rr / NG) % NG);
      float cn3 = grid20(rr % NG);
      int fi = t;
      int f1 = fi / (NF * NF);
      int fc = fi % (NF * NF);
      out[0] = (float)(m + 1);
      out[1] = finev(cn1, f1);
      out[2] = finev(cn2, fc / NF);
      out[3] = finev(cn3, fc % NF);
    }
  }
}

extern "C" void kernel_launch(void* const* d_in, const int* in_sizes, int n_in,
                              void* d_out, int out_size, void* d_ws, size_t ws_size,
                              hipStream_t stream) {
  const float* x = (const float*)d_in[0];
  const int* freqp = (const int*)d_in[1];
  float* out = (float*)d_out;
  float* fws = (float*)d_ws;

  double* D0  = (double*)(fws + OFF_DWS);   // byte 90272, 8-aligned
  double* dstt = D0;                        // [1]
  double* bvc = D0 + 1;                     // NCC2
  double* bvf = bvc + NCC2;                 // NFC2
  int* btc = (int*)(bvf + NFC2);            // NCC2
  int* btf = btc + NCC2;                    // NFC2

  hipLaunchKernelGGL(k_init,   dim3(5),    dim3(256), 0, stream, x, freqp, fws, dstt);
  hipLaunchKernelGGL(k_coarse, dim3(NCC2), dim3(256), 0, stream, fws, dstt, bvc, btc);
  hipLaunchKernelGGL(k_fine,   dim3(NFC2), dim3(256), 0, stream, fws, dstt, bvc, btc, bvf, btf);
  hipLaunchKernelGGL(k_out,    dim3(1),    dim3(256), 0, stream, bvc, btc, bvf, btf, out);
}

// Round 17
// 50.475 us; speedup vs baseline: 1.9865x; 1.3864x over previous
//
#include <hip/hip_runtime.h>

#define L    2048
#define HALF 1024
#define NM   10
#define NG   20
#define NF   30

#define NCC2 2000   // coarse blocks = (m, i2, i3-pair)
#define NFC2 450    // fine blocks   = (j2, j3-pair)

// ---- float workspace layout (float indices) ----
#define OFF_SC   0                        // float2 sc[1024] = {sin^2, sin*td}
#define OFF_TAB  2048                     // float2 tab[NM*HALF] = {lc, ls}
#define OFF_G20  (2048 + 2*NM*HALF)       // 22528: grid20[20]
#define OFF_R20  (OFF_G20 + 20)           // -1/grid20 [20]
#define OFF_DWS  (OFF_R20 + 20)           // 22568 floats -> byte 90272 (%8==0)

#define EXP2F(x) __builtin_amdgcn_exp2f(x)
#define LOG2F(x) __builtin_amdgcn_logf(x)

typedef float f32x2 __attribute__((ext_vector_type(2)));

// packed helpers: ext-vector ops lower to v_pk_mul_f32 / v_pk_fma_f32 on CDNA
__device__ __forceinline__ f32x2 pk_mul(f32x2 a, f32x2 b) { return a * b; }
__device__ __forceinline__ f32x2 pk_fma(f32x2 a, f32x2 b, f32x2 c) {
  return __builtin_elementwise_fma(a, b, c);
}
__device__ __forceinline__ f32x2 pk_exp2(f32x2 v) {
  f32x2 e; e.x = EXP2F(v.x); e.y = EXP2F(v.y); return e;
}

__device__ __forceinline__ float grid20(int i) {
  double e = -1.0 + 2.0 * (double)i / 19.0;
  return (float)exp2(e * 3.3219280948873623478703194294894);
}
__device__ __forceinline__ float finev(float c, int j) {
  return (float)((double)c * 0.8 + (double)j * ((double)c * 0.4 / 29.0));
}
__device__ __forceinline__ double mse_from(double sgg2, double sgt, double sum_tt) {
  double S = sgg2; if (S < 0.0) S = 0.0;
  double d = sqrt(S / (double)(L - 1)) + 1e-6;
  return (S / (d * d) - 2.0 * sgt / d + sum_tt) / (double)L;
}
__device__ __forceinline__ void vt_wave_reduce(double& v, int& t) {
  for (int o = 32; o > 0; o >>= 1) {
    double ov = __shfl_down(v, o);
    int ot = __shfl_down(t, o);
    if (ov < v || (ov == v && ot < t)) { v = ov; t = ot; }
  }
}
__device__ __forceinline__ void vt_block_merge(double& v, int& t, double* sv, int* st) {
  int lane = threadIdx.x & 63, w = threadIdx.x >> 6;
  vt_wave_reduce(v, t);
  if (lane == 0) { sv[w] = v; st[w] = t; }
  __syncthreads();
  if (threadIdx.x == 0) {
    for (int k = 1; k < 4; k++)
      if (sv[k] < v || (sv[k] == v && st[k] < t)) { v = sv[k]; t = st[k]; }
  }
}

// ---------------- K1: setup (block 0) + tables (blocks 1..4, recurrence) ---
__global__ __launch_bounds__(256) void k_init(const float* __restrict__ x,
                                              const int* __restrict__ freqp,
                                              float* __restrict__ fws,
                                              double* __restrict__ dstt) {
  if (blockIdx.x == 0) {
    int tid = threadIdx.x;
    int lane = tid & 63, w = tid >> 6;
    __shared__ double sh[8];
    __shared__ double s_mean, s_d;

    double sx = 0.0, sxx = 0.0;
    for (int l = tid; l < L; l += 256) {
      double v = (double)x[l];
      sx += v; sxx += v * v;
    }
    for (int o = 32; o > 0; o >>= 1) { sx += __shfl_down(sx, o); sxx += __shfl_down(sxx, o); }
    if (lane == 0) { sh[w] = sx; sh[4 + w] = sxx; }
    __syncthreads();
    if (tid == 0) {
      sx = sh[0] + sh[1] + sh[2] + sh[3];
      sxx = sh[4] + sh[5] + sh[6] + sh[7];
      double mean = sx / (double)L;
      double S = sxx - sx * sx / (double)L; if (S < 0.0) S = 0.0;
      s_mean = mean; s_d = sqrt(S / (double)(L - 1)) + 1e-6;
    }
    __syncthreads();
    double mean = s_mean, d = s_d;
    double freq = (double)freqp[0];

    double stt = 0.0;
    for (int l = tid; l < HALF; l += 256) {
      float tva = (float)(((double)x[l] - mean) / d);
      float tvb = (float)(((double)x[L - 1 - l] - mean) / d);
      float tdv = tva - tvb;
      double t = -1.0 + 2.0 * (double)l / 2047.0;
      float spv = (float)sin(6.2831853071795864769 * freq * t);
      float2 scv; scv.x = spv * spv; scv.y = spv * tdv;
      reinterpret_cast<float2*>(fws + OFF_SC)[l] = scv;
      stt += (double)tva * (double)tva + (double)tvb * (double)tvb;
    }
    for (int o = 32; o > 0; o >>= 1) { stt += __shfl_down(stt, o); }
    __syncthreads();
    if (lane == 0) { sh[w] = stt; }
    __syncthreads();
    if (tid == 0) { dstt[0] = sh[0] + sh[1] + sh[2] + sh[3]; }
  } else {
    // blocks 1..4: one thread per l; sincos once, then 10 angle-addition steps
    int l = (blockIdx.x - 1) * 256 + threadIdx.x;   // [0, 1024)
    double freq = (double)freqp[0];
    double t = -1.0 + 2.0 * (double)l / 2047.0;
    double theta = 6.2831853071795864769 * freq * t * 0.25;   // phi/4
    double s1, c1;
    sincos(theta, &s1, &c1);
    double sk = s1, ck = c1;
    float2* tabp = reinterpret_cast<float2*>(fws + OFF_TAB);
#pragma unroll
    for (int m = 0; m < NM; ++m) {
      float2 v;
      v.x = fmaxf(LOG2F(fabsf((float)ck)), -1.0e4f);
      v.y = fmaxf(LOG2F(fabsf((float)sk)), -1.0e4f);
      tabp[m * HALF + l] = v;
      double sn = sk * c1 + ck * s1;
      double cn = ck * c1 - sk * s1;
      sk = sn; ck = cn;
    }
    if (blockIdx.x == 1 && threadIdx.x < NG) {
      float g = grid20(threadIdx.x);
      fws[OFF_G20 + threadIdx.x] = g;
      fws[OFF_R20 + threadIdx.x] = -1.0f / g;
    }
  }
}

// ---------------- K2: coarse scan — packed-f32 pairs, raw v_exp ------------
// block = (m, i2, i3pair); LDS pair rows:
//   row_ls[q] = {lsA(2q), lsA(2q+1), lsB(2q), lsB(2q+1)}
//   row_sc[q] = {sx(2q),  sx(2q+1),  sy(2q),  sy(2q+1)}
// wave w owns i1 in [5w,5w+5): passes {0,1},{2,3},{4}; f32x2 accumulators.
__global__ __launch_bounds__(256) void k_coarse(const float* __restrict__ fws,
                                                const double* __restrict__ dstt,
                                                double* __restrict__ bv,
                                                int* __restrict__ bt) {
  __shared__ float4 row_ls[512];   // 8 KB
  __shared__ float4 row_sc[512];   // 8 KB
  __shared__ float2 cells[40];
  __shared__ int cellt[40];
  int tid = threadIdx.x, lane = tid & 63, w = tid >> 6;
  int b = blockIdx.x;
  int m = b / 200;
  int rem = b % 200;
  int i2 = rem / 10;
  int p3 = rem % 10;
  int i3A = 2 * p3;
  float n2 = fws[OFF_G20 + i2];
  float n3A = fws[OFF_G20 + i3A];
  float n3B = fws[OFF_G20 + i3A + 1];

  const float2* tab = reinterpret_cast<const float2*>(fws + OFF_TAB) + m * HALF;
  const float2* sc = reinterpret_cast<const float2*>(fws + OFF_SC);
#pragma unroll
  for (int k = 0; k < 2; k++) {
    int q = tid + k * 256;          // pair index [0,512)
    int e0 = 2 * q, e1 = e0 + 1;
    float2 tb0 = tab[e0], tb1 = tab[e1];
    float2 s0 = sc[e0], s1 = sc[e1];
    float a20 = EXP2F(n2 * tb0.x), a21 = EXP2F(n2 * tb1.x);
    float4 ls;
    ls.x = LOG2F(a20 + EXP2F(n3A * tb0.y));
    ls.y = LOG2F(a21 + EXP2F(n3A * tb1.y));
    ls.z = LOG2F(a20 + EXP2F(n3B * tb0.y));
    ls.w = LOG2F(a21 + EXP2F(n3B * tb1.y));
    row_ls[q] = ls;
    row_sc[q] = make_float4(s0.x, s1.x, s0.y, s1.y);
  }
  __syncthreads();

#pragma unroll
  for (int pass = 0; pass < 3; ++pass) {
    const bool two = (pass < 2);
    int i1a = w * 5 + pass * 2;
    float r0s = fws[OFF_R20 + i1a];
    float r1s = two ? fws[OFF_R20 + i1a + 1] : 0.0f;
    f32x2 r0 = {r0s, r0s}, r1 = {r1s, r1s};
    f32x2 z = {0.0f, 0.0f};
    f32x2 aA0 = z, tA0 = z, aB0 = z, tB0 = z;
    f32x2 aA1 = z, tA1 = z, aB1 = z, tB1 = z;
#pragma unroll 4
    for (int it = 0; it < 8; ++it) {
      int q = lane + it * 64;
      float4 ls4 = row_ls[q];
      float4 sc4 = row_sc[q];
      f32x2 lsA = {ls4.x, ls4.y}, lsB = {ls4.z, ls4.w};
      f32x2 sx = {sc4.x, sc4.y}, sy = {sc4.z, sc4.w};
      f32x2 e, e2;
      e = pk_exp2(pk_mul(r0, lsA)); e2 = pk_mul(e, e);
      aA0 = pk_fma(e2, sx, aA0); tA0 = pk_fma(e, sy, tA0);
      e = pk_exp2(pk_mul(r0, lsB)); e2 = pk_mul(e, e);
      aB0 = pk_fma(e2, sx, aB0); tB0 = pk_fma(e, sy, tB0);
      if (two) {
        e = pk_exp2(pk_mul(r1, lsA)); e2 = pk_mul(e, e);
        aA1 = pk_fma(e2, sx, aA1); tA1 = pk_fma(e, sy, tA1);
        e = pk_exp2(pk_mul(r1, lsB)); e2 = pk_mul(e, e);
        aB1 = pk_fma(e2, sx, aB1); tB1 = pk_fma(e, sy, tB1);
      }
    }
    float aA0s = aA0.x + aA0.y, tA0s = tA0.x + tA0.y;
    float aB0s = aB0.x + aB0.y, tB0s = tB0.x + tB0.y;
    float aA1s = aA1.x + aA1.y, tA1s = tA1.x + tA1.y;
    float aB1s = aB1.x + aB1.y, tB1s = tB1.x + tB1.y;
    for (int o = 32; o > 0; o >>= 1) {
      aA0s += __shfl_down(aA0s, o); tA0s += __shfl_down(tA0s, o);
      aB0s += __shfl_down(aB0s, o); tB0s += __shfl_down(tB0s, o);
      if (two) {
        aA1s += __shfl_down(aA1s, o); tA1s += __shfl_down(tA1s, o);
        aB1s += __shfl_down(aB1s, o); tB1s += __shfl_down(tB1s, o);
      }
    }
    if (lane == 0) {
      int t0 = ((m * NG + i1a) * NG + i2) * NG + i3A;   // ref flat index
      int s0 = w * 10 + pass * 4;
      cells[s0]     = make_float2(aA0s, tA0s); cellt[s0]     = t0;
      cells[s0 + 1] = make_float2(aB0s, tB0s); cellt[s0 + 1] = t0 + 1;
      if (two) {
        cells[s0 + 2] = make_float2(aA1s, tA1s); cellt[s0 + 2] = t0 + NG * NG;
        cells[s0 + 3] = make_float2(aB1s, tB1s); cellt[s0 + 3] = t0 + NG * NG + 1;
      }
    }
  }
  __syncthreads();

  if (w == 0) {
    double v = 1e300; int t = 0x7fffffff;
    if (lane < 40) {
      float2 p = cells[lane];
      v = mse_from(2.0 * (double)p.x, (double)p.y, dstt[0]);
      t = cellt[lane];
    }
    vt_wave_reduce(v, t);
    if (lane == 0) { bv[b] = v; bt[b] = t; }
  }
}

// ---------------- K3: fine scan — coarse argmin preamble, packed pairs -----
__global__ __launch_bounds__(256) void k_fine(const float* __restrict__ fws,
                                              const double* __restrict__ dstt,
                                              const double* __restrict__ bvc,
                                              const int* __restrict__ btc,
                                              double* __restrict__ bvf,
                                              int* __restrict__ btf) {
  __shared__ float4 row_ls[512];
  __shared__ float4 row_sc[512];
  __shared__ float2 cells[60];
  __shared__ int cellt[60];
  __shared__ double sv[4];
  __shared__ int st[4];
  __shared__ float s_cn[4];
  {
    double v = 1e300; int t = 0x7fffffff;
    for (int i = threadIdx.x; i < NCC2; i += 256) {
      double ov = bvc[i]; int ot = btc[i];
      if (ov < v || (ov == v && ot < t)) { v = ov; t = ot; }
    }
    vt_block_merge(v, t, sv, st);
    if (threadIdx.x == 0) {
      int ci = t;
      int m  = ci / (NG * NG * NG);
      int rr = ci % (NG * NG * NG);
      s_cn[0] = grid20(rr / (NG * NG));
      s_cn[1] = grid20((rr / NG) % NG);
      s_cn[2] = grid20(rr % NG);
      s_cn[3] = (float)m;
    }
  }
  __syncthreads();
  float cn1 = s_cn[0], cn2 = s_cn[1], cn3 = s_cn[2];
  int m = (int)s_cn[3];

  int tid = threadIdx.x, lane = tid & 63, w = tid >> 6;
  int b = blockIdx.x;
  int j2 = b / 15;
  int p3 = b % 15;
  int j3A = 2 * p3;
  float n2 = finev(cn2, j2);
  float n3A = finev(cn3, j3A);
  float n3B = finev(cn3, j3A + 1);

  const float2* tab = reinterpret_cast<const float2*>(fws + OFF_TAB) + m * HALF;
  const float2* sc = reinterpret_cast<const float2*>(fws + OFF_SC);
#pragma unroll
  for (int k = 0; k < 2; k++) {
    int q = tid + k * 256;
    int e0 = 2 * q, e1 = e0 + 1;
    float2 tb0 = tab[e0], tb1 = tab[e1];
    float2 s0 = sc[e0], s1 = sc[e1];
    float a20 = EXP2F(n2 * tb0.x), a21 = EXP2F(n2 * tb1.x);
    float4 ls;
    ls.x = LOG2F(a20 + EXP2F(n3A * tb0.y));
    ls.y = LOG2F(a21 + EXP2F(n3A * tb1.y));
    ls.z = LOG2F(a20 + EXP2F(n3B * tb0.y));
    ls.w = LOG2F(a21 + EXP2F(n3B * tb1.y));
    row_ls[q] = ls;
    row_sc[q] = make_float4(s0.x, s1.x, s0.y, s1.y);
  }
  __syncthreads();

  int npairs = (w < 3) ? 4 : 3;   // j1 counts 8,8,8,6
  for (int pp = 0; pp < npairs; ++pp) {
    int j1a = w * 8 + pp * 2;
    float r0s = -1.0f / finev(cn1, j1a);
    float r1s = -1.0f / finev(cn1, j1a + 1);
    f32x2 r0 = {r0s, r0s}, r1 = {r1s, r1s};
    f32x2 z = {0.0f, 0.0f};
    f32x2 aA0 = z, tA0 = z, aB0 = z, tB0 = z;
    f32x2 aA1 = z, tA1 = z, aB1 = z, tB1 = z;
#pragma unroll 4
    for (int it = 0; it < 8; ++it) {
      int q = lane + it * 64;
      float4 ls4 = row_ls[q];
      float4 sc4 = row_sc[q];
      f32x2 lsA = {ls4.x, ls4.y}, lsB = {ls4.z, ls4.w};
      f32x2 sx = {sc4.x, sc4.y}, sy = {sc4.z, sc4.w};
      f32x2 e, e2;
      e = pk_exp2(pk_mul(r0, lsA)); e2 = pk_mul(e, e);
      aA0 = pk_fma(e2, sx, aA0); tA0 = pk_fma(e, sy, tA0);
      e = pk_exp2(pk_mul(r0, lsB)); e2 = pk_mul(e, e);
      aB0 = pk_fma(e2, sx, aB0); tB0 = pk_fma(e, sy, tB0);
      e = pk_exp2(pk_mul(r1, lsA)); e2 = pk_mul(e, e);
      aA1 = pk_fma(e2, sx, aA1); tA1 = pk_fma(e, sy, tA1);
      e = pk_exp2(pk_mul(r1, lsB)); e2 = pk_mul(e, e);
      aB1 = pk_fma(e2, sx, aB1); tB1 = pk_fma(e, sy, tB1);
    }
    float aA0s = aA0.x + aA0.y, tA0s = tA0.x + tA0.y;
    float aB0s = aB0.x + aB0.y, tB0s = tB0.x + tB0.y;
    float aA1s = aA1.x + aA1.y, tA1s = tA1.x + tA1.y;
    float aB1s = aB1.x + aB1.y, tB1s = tB1.x + tB1.y;
    for (int o = 32; o > 0; o >>= 1) {
      aA0s += __shfl_down(aA0s, o); tA0s += __shfl_down(tA0s, o);
      aB0s += __shfl_down(aB0s, o); tB0s += __shfl_down(tB0s, o);
      aA1s += __shfl_down(aA1s, o); tA1s += __shfl_down(tA1s, o);
      aB1s += __shfl_down(aB1s, o); tB1s += __shfl_down(tB1s, o);
    }
    if (lane == 0) {
      int t0 = (j1a * NF + j2) * NF + j3A;   // fine flat index
      int s0 = w * 16 + pp * 4;
      cells[s0]     = make_float2(aA0s, tA0s); cellt[s0]     = t0;
      cells[s0 + 1] = make_float2(aB0s, tB0s); cellt[s0 + 1] = t0 + 1;
      cells[s0 + 2] = make_float2(aA1s, tA1s); cellt[s0 + 2] = t0 + NF * NF;
      cells[s0 + 3] = make_float2(aB1s, tB1s); cellt[s0 + 3] = t0 + NF * NF + 1;
    }
  }
  __syncthreads();

  if (w == 0) {
    double v = 1e300; int t = 0x7fffffff;
    if (lane < 60) {
      float2 p = cells[lane];
      v = mse_from(2.0 * (double)p.x, (double)p.y, dstt[0]);
      t = cellt[lane];
    }
    vt_wave_reduce(v, t);
    if (lane == 0) { bvf[b] = v; btf[b] = t; }
  }
}

// ---------------- K4: final argmins + emit ---------------------------------
__global__ __launch_bounds__(256) void k_out(const double* __restrict__ bvc,
                                             const int* __restrict__ btc,
                                             const double* __restrict__ bvf,
                                             const int* __restrict__ btf,
                                             float* __restrict__ out) {
  __shared__ double sv[4];
  __shared__ int st[4];
  __shared__ int s_ci;
  {
    double v = 1e300; int t = 0x7fffffff;
    for (int i = threadIdx.x; i < NCC2; i += 256) {
      double ov = bvc[i]; int ot = btc[i];
      if (ov < v || (ov == v && ot < t)) { v = ov; t = ot; }
    }
    vt_block_merge(v, t, sv, st);
    if (threadIdx.x == 0) s_ci = t;
  }
  __syncthreads();
  {
    double v = 1e300; int t = 0x7fffffff;
    for (int i = threadIdx.x; i < NFC2; i += 256) {
      double ov = bvf[i]; int ot = btf[i];
      if (ov < v || (ov == v && ot < t)) { v = ov; t = ot; }
    }
    vt_block_merge(v, t, sv, st);
    if (threadIdx.x == 0) {
      int ci = s_ci;
      int m  = ci / (NG * NG * NG);
      int rr = ci % (NG * NG * NG);
      float cn1 = grid20(rr / (NG * NG));
      float cn2 = grid20((rr / NG) % NG);
      float cn3 = grid20(rr % NG);
      int fi = t;
      int f1 = fi / (NF * NF);
      int fc = fi % (NF * NF);
      out[0] = (float)(m + 1);
      out[1] = finev(cn1, f1);
      out[2] = finev(cn2, fc / NF);
      out[3] = finev(cn3, fc % NF);
    }
  }
}

extern "C" void kernel_launch(void* const* d_in, const int* in_sizes, int n_in,
                              void* d_out, int out_size, void* d_ws, size_t ws_size,
                              hipStream_t stream) {
  const float* x = (const float*)d_in[0];
  const int* freqp = (const int*)d_in[1];
  float* out = (float*)d_out;
  float* fws = (float*)d_ws;

  double* D0  = (double*)(fws + OFF_DWS);   // byte 90272, 8-aligned
  double* dstt = D0;                        // [1]
  double* bvc = D0 + 1;                     // NCC2
  double* bvf = bvc + NCC2;                 // NFC2
  int* btc = (int*)(bvf + NFC2);            // NCC2
  int* btf = btc + NCC2;                    // NFC2

  hipLaunchKernelGGL(k_init,   dim3(5),    dim3(256), 0, stream, x, freqp, fws, dstt);
  hipLaunchKernelGGL(k_coarse, dim3(NCC2), dim3(256), 0, stream, fws, dstt, bvc, btc);
  hipLaunchKernelGGL(k_fine,   dim3(NFC2), dim3(256), 0, stream, fws, dstt, bvc, btc, bvf, btf);
  hipLaunchKernelGGL(k_out,    dim3(1),    dim3(256), 0, stream, bvc, btc, bvf, btf, out);
}